// Round 5
// baseline (655.448 us; speedup 1.0000x reference)
//
#include <hip/hip_runtime.h>
#include <hip/hip_bf16.h>
#include <stdint.h>

#define HDIM 1024
#define IDIM 2048
#define NEXP 8
#define NEXP1 9      // 8 routed + 1 shared (index 8)
#define TTOK 4096
#define REPS 1e-5f

typedef __bf16 bf16_t;
typedef __bf16 bf16x8 __attribute__((ext_vector_type(8)));
typedef __bf16 bf16x4 __attribute__((ext_vector_type(4)));
typedef float f32x4 __attribute__((ext_vector_type(4)));

// async global->LDS DMA, 16 B per lane. dst must be wave-uniform; HW adds lane*16.
__device__ __forceinline__ void gl_lds16(const bf16_t* g, bf16_t* l) {
    __builtin_amdgcn_global_load_lds(
        (const __attribute__((address_space(1))) void*)g,
        (__attribute__((address_space(3))) void*)l, 16, 0, 0);
}

// ---------------- fp32 -> bf16 convert (contiguous) ----------------
__global__ __launch_bounds__(256) void k_convert(const float* __restrict__ src,
                                                 bf16_t* __restrict__ dst) {
    size_t i = ((size_t)blockIdx.x * 256 + threadIdx.x) * 4;
    float4 v = *(const float4*)(src + i);
    bf16x4 o = {(__bf16)v.x, (__bf16)v.y, (__bf16)v.z, (__bf16)v.w};
    *(bf16x4*)(dst + i) = o;
}

// ---- transpose core: src [R][C] f32 -> dst [C][R] bf16, one 128(row)x64(col) tile ----
__device__ __forceinline__ void tr_tile(const float* __restrict__ src, bf16_t* __restrict__ dst,
                                        int R, int C, int c0, int r0, bf16_t* lds) {
    int tid = threadIdx.x;
    // phase 1: lane loads float4, converts, 8B store to XOR-swizzled chunk
    int rlo = tid >> 4, chunk = tid & 15;
    for (int p = 0; p < 8; p++) {
        int r = p * 16 + rlo;
        float4 v = *(const float4*)(src + (size_t)(r0 + r) * C + c0 + chunk * 4);
        bf16x4 o = {(__bf16)v.x, (__bf16)v.y, (__bf16)v.z, (__bf16)v.w};
        *(bf16x4*)(lds + r * 64 + (chunk ^ (p & 7)) * 4) = o;
    }
    __syncthreads();
    // phase 2: thread = (col-pair c2 0..31, row-half rh 0..7); b32 reads, pack, 32B col stores
    int c2 = tid & 31, rh = tid >> 5;
    uint32_t d[16];
    for (int i = 0; i < 16; i++) {
        int r = rh * 16 + i;
        d[i] = *(const uint32_t*)(lds + r * 64 + ((c2 >> 1) ^ (rh & 7)) * 4 + (c2 & 1) * 2);
    }
    uint32_t o0[8], o1[8];
    for (int j = 0; j < 8; j++) {
        uint32_t a = d[2 * j], b = d[2 * j + 1];
        o0[j] = (a & 0xffffu) | (b << 16);
        o1[j] = (a >> 16) | (b & 0xffff0000u);
    }
    bf16_t* p0 = dst + (size_t)(c0 + 2 * c2) * R + r0 + rh * 16;
    bf16_t* p1 = p0 + R;
    *(uint4*)p0 = *(uint4*)&o0[0];
    *(uint4*)(p0 + 8) = *(uint4*)&o0[4];
    *(uint4*)p1 = *(uint4*)&o1[0];
    *(uint4*)(p1 + 8) = *(uint4*)&o1[4];
}

// [H][I] sources (eg, eu, sg, su) -> [I][H] bf16. z: 0..7 eg, 8..15 eu, 16 sg, 17 su.
__global__ __launch_bounds__(256) void k_tr_HI(const float* __restrict__ eg,
                                               const float* __restrict__ eu,
                                               const float* __restrict__ sg,
                                               const float* __restrict__ su,
                                               bf16_t* __restrict__ WgT,
                                               bf16_t* __restrict__ WuT) {
    __shared__ __align__(16) bf16_t lds[128 * 64];
    int z = blockIdx.z;
    const float* src;
    bf16_t* dst;
    size_t msz = (size_t)HDIM * IDIM;
    if (z < 8)       { src = eg + z * msz;        dst = WgT + z * msz; }
    else if (z < 16) { src = eu + (z - 8) * msz;  dst = WuT + (z - 8) * msz; }
    else if (z == 16){ src = sg;                  dst = WgT + 8 * msz; }
    else             { src = su;                  dst = WuT + 8 * msz; }
    tr_tile(src, dst, HDIM, IDIM, blockIdx.x * 64, blockIdx.y * 128, lds);
}

// [I][H] sources (ed, sd) -> [H][I] bf16. z: 0..7 ed, 8 sd.
__global__ __launch_bounds__(256) void k_tr_IH(const float* __restrict__ ed,
                                               const float* __restrict__ sd,
                                               bf16_t* __restrict__ WdT) {
    __shared__ __align__(16) bf16_t lds[128 * 64];
    int z = blockIdx.z;
    size_t msz = (size_t)HDIM * IDIM;
    const float* src = (z < 8) ? ed + z * msz : sd;
    bf16_t* dst = WdT + ((z < 8) ? z : 8) * msz;
    tr_tile(src, dst, IDIM, HDIM, blockIdx.x * 64, blockIdx.y * 128, lds);
}

// ---------------- router prep: A = tp_w @ gate_w [H,8]; bg = tp_b @ gate_w [8] ----------------
__global__ __launch_bounds__(256) void k_router_prep(const float* __restrict__ tp_w,
                                                     const float* __restrict__ tp_b,
                                                     const float* __restrict__ gw,
                                                     float* __restrict__ A_r,
                                                     float* __restrict__ bg) {
    int idx = blockIdx.x * 256 + threadIdx.x;
    if (idx < HDIM * NEXP) {
        int h = idx >> 3, e = idx & 7;
        const float* wr = tp_w + (size_t)h * HDIM;
        float acc = 0.f;
        for (int j = 0; j < HDIM; j++) acc = fmaf(wr[j], gw[j * NEXP + e], acc);
        A_r[idx] = acc;
    } else if (idx < HDIM * NEXP + NEXP) {
        int e = idx - HDIM * NEXP;
        float acc = 0.f;
        for (int j = 0; j < HDIM; j++) acc = fmaf(tp_b[j], gw[j * NEXP + e], acc);
        bg[e] = acc;
    }
}

// ---------------- router: logits, softmax, top-2, bucket by expert (+ shared-expert fill) -----
__global__ __launch_bounds__(256) void k_router(const float* __restrict__ x,
                                                const float* __restrict__ tcx,
                                                const float* __restrict__ gw,
                                                const float* __restrict__ A_r,
                                                const float* __restrict__ bg,
                                                int* __restrict__ cnt, int* __restrict__ tok,
                                                float* __restrict__ wl, int* __restrict__ sl) {
    int wave = threadIdx.x >> 6, lane = threadIdx.x & 63;
    int t = blockIdx.x * 4 + wave;
    const float* xr = x + (size_t)t * HDIM;
    const float* tr = tcx + (size_t)t * HDIM;
    float lg[NEXP];
    for (int e = 0; e < NEXP; e++) lg[e] = 0.f;
    for (int h = lane; h < HDIM; h += 64) {
        float xv = xr[h], tv = tr[h];
        const float4* g4 = (const float4*)(gw + h * NEXP);
        const float4* a4 = (const float4*)(A_r + h * NEXP);
        float4 g0 = g4[0], g1 = g4[1], a0 = a4[0], a1 = a4[1];
        lg[0] += xv * g0.x + tv * a0.x;
        lg[1] += xv * g0.y + tv * a0.y;
        lg[2] += xv * g0.z + tv * a0.z;
        lg[3] += xv * g0.w + tv * a0.w;
        lg[4] += xv * g1.x + tv * a1.x;
        lg[5] += xv * g1.y + tv * a1.y;
        lg[6] += xv * g1.z + tv * a1.z;
        lg[7] += xv * g1.w + tv * a1.w;
    }
    for (int off = 32; off > 0; off >>= 1)
        for (int e = 0; e < NEXP; e++) lg[e] += __shfl_xor(lg[e], off);
    if (lane == 1) {  // shared-expert identity entry (fused former k_fill_shared)
        tok[NEXP * TTOK + t] = t;
        wl[NEXP * TTOK + t] = 1.f;
        sl[NEXP * TTOK + t] = 2 * TTOK + t;
        if (t == 0) cnt[NEXP] = TTOK;
    }
    if (lane == 0) {
        float m = -1e30f;
        for (int e = 0; e < NEXP; e++) {
            lg[e] += bg[e];
            m = fmaxf(m, lg[e]);
        }
        float p[NEXP], Z = 0.f;
        for (int e = 0; e < NEXP; e++) {
            p[e] = __expf(lg[e] - m);
            Z += p[e];
        }
        for (int e = 0; e < NEXP; e++) p[e] /= Z;
        int i1 = 0;
        float b1 = p[0];
        for (int e = 1; e < NEXP; e++)
            if (p[e] > b1) { b1 = p[e]; i1 = e; }   // strict > : lowest index wins ties (jax top_k)
        int i2 = -1;
        float b2 = -1.f;
        for (int e = 0; e < NEXP; e++) {
            if (e == i1) continue;
            if (p[e] > b2) { b2 = p[e]; i2 = e; }
        }
        float s = b1 + b2 + REPS;
        float w1 = b1 / s, w2 = b2 / s;
        int p1 = atomicAdd(&cnt[i1], 1);
        tok[i1 * TTOK + p1] = t;
        wl[i1 * TTOK + p1] = w1;
        sl[i1 * TTOK + p1] = 2 * t;
        int p2 = atomicAdd(&cnt[i2], 1);
        tok[i2 * TTOK + p2] = t;
        wl[i2 * TTOK + p2] = w2;
        sl[i2 * TTOK + p2] = 2 * t + 1;
    }
}

// ---------------- gate/up GEMM, 128x128 tile (async LDS staging, xor-swizzled) ----------------
__global__ __launch_bounds__(256, 2) void k_gateup(const bf16_t* __restrict__ Xb,
                                                   const bf16_t* __restrict__ WgT,
                                                   const bf16_t* __restrict__ WuT,
                                                   bf16_t* __restrict__ Hout,
                                                   const int* __restrict__ tok_l,
                                                   const float* __restrict__ w_l,
                                                   const int* __restrict__ slot_l,
                                                   const int* __restrict__ cnt) {
    int e = blockIdx.z;
    int rows = cnt[e];
    int m0 = blockIdx.y * 128;
    if (m0 >= rows) return;
    int n0 = blockIdx.x * 128;
    const bf16_t* Wg = WgT + (size_t)e * IDIM * HDIM;
    const bf16_t* Wu = WuT + (size_t)e * IDIM * HDIM;
    const int* tl = tok_l + e * TTOK;
    const float* wlp = w_l + e * TTOK;
    const int* sl = slot_l + e * TTOK;

    __shared__ __align__(16) bf16_t As[128 * 64];
    __shared__ __align__(16) bf16_t Bg[128 * 64];
    __shared__ __align__(16) bf16_t Bu[128 * 64];

    int tid = threadIdx.x;
    int lane = tid & 63, wave = tid >> 6;
    int lrow = lane >> 3;                      // 0..7 within an issue
    int lchunk = (lane & 7) ^ lrow;            // inverse swizzle on the source side

    const bf16_t* asrc[4];
    const bf16_t* gsrc[4];
    const bf16_t* usrc[4];
    for (int j = 0; j < 4; j++) {
        int r = (wave * 4 + j) * 8 + lrow;     // tile row 0..127
        int arow = tl[min(m0 + r, rows - 1)];
        asrc[j] = Xb + (size_t)arow * HDIM + lchunk * 8;
        gsrc[j] = Wg + (size_t)(n0 + r) * HDIM + lchunk * 8;
        usrc[j] = Wu + (size_t)(n0 + r) * HDIM + lchunk * 8;
    }

    f32x4 accg[4][4], accu[4][4];
    for (int a = 0; a < 4; a++)
        for (int b = 0; b < 4; b++) {
            accg[a][b] = (f32x4){0.f, 0.f, 0.f, 0.f};
            accu[a][b] = (f32x4){0.f, 0.f, 0.f, 0.f};
        }
    int wm = wave >> 1, wn = wave & 1;
    int lm = lane & 15, quad = lane >> 4, x7 = lm & 7;

    for (int k0 = 0; k0 < HDIM; k0 += 64) {
        for (int j = 0; j < 4; j++) {
            gl_lds16(asrc[j] + k0, As + (wave * 4 + j) * 512);
            gl_lds16(gsrc[j] + k0, Bg + (wave * 4 + j) * 512);
            gl_lds16(usrc[j] + k0, Bu + (wave * 4 + j) * 512);
        }
        __syncthreads();
        for (int kk = 0; kk < 2; kk++) {
            int cg = ((kk * 4 + quad) ^ x7) * 8;
            bf16x8 af[4], bgf[4], buf_[4];
            for (int mi = 0; mi < 4; mi++)
                af[mi] = *(const bf16x8*)&As[(wm * 64 + mi * 16 + lm) * 64 + cg];
            for (int ni = 0; ni < 4; ni++) {
                bgf[ni] = *(const bf16x8*)&Bg[(wn * 64 + ni * 16 + lm) * 64 + cg];
                buf_[ni] = *(const bf16x8*)&Bu[(wn * 64 + ni * 16 + lm) * 64 + cg];
            }
            for (int mi = 0; mi < 4; mi++)
                for (int ni = 0; ni < 4; ni++) {
                    accg[mi][ni] = __builtin_amdgcn_mfma_f32_16x16x32_bf16(af[mi], bgf[ni],
                                                                           accg[mi][ni], 0, 0, 0);
                    accu[mi][ni] = __builtin_amdgcn_mfma_f32_16x16x32_bf16(af[mi], buf_[ni],
                                                                           accu[mi][ni], 0, 0, 0);
                }
        }
        __syncthreads();
    }
    for (int mi = 0; mi < 4; mi++)
        for (int j = 0; j < 4; j++) {
            int r = m0 + wm * 64 + mi * 16 + quad * 4 + j;  // C/D: row = quad*4+reg
            if (r >= rows) continue;
            int srow = sl[r];
            float w = wlp[r];
            bf16_t* hp = Hout + (size_t)srow * IDIM + n0 + wn * 64 + lm;  // col = lane&15
            for (int ni = 0; ni < 4; ni++) {
                float g = accg[mi][ni][j];
                float u = accu[mi][ni][j];
                hp[ni * 16] = (bf16_t)(g / (1.f + __expf(-g)) * u * w);
            }
        }
}

// ---------------- down GEMM: eout[slot] = h[slot] @ Wd (async staging, swizzled) ----------------
__global__ __launch_bounds__(256, 2) void k_down(const bf16_t* __restrict__ Hin,
                                                 const bf16_t* __restrict__ WdT,
                                                 bf16_t* __restrict__ Eout,
                                                 const int* __restrict__ slot_l,
                                                 const int* __restrict__ cnt) {
    int e = blockIdx.z;
    int rows = cnt[e];
    int m0 = blockIdx.y * 128;
    if (m0 >= rows) return;
    int n0 = blockIdx.x * 128;
    const bf16_t* Wd = WdT + (size_t)e * HDIM * IDIM;
    const int* sl = slot_l + e * TTOK;

    __shared__ __align__(16) bf16_t As[128 * 64];
    __shared__ __align__(16) bf16_t Bs[128 * 64];

    int tid = threadIdx.x, lane = tid & 63, wave = tid >> 6;
    int lrow = lane >> 3;
    int lchunk = (lane & 7) ^ lrow;

    const bf16_t* asrc[4];
    const bf16_t* bsrc[4];
    for (int j = 0; j < 4; j++) {
        int r = (wave * 4 + j) * 8 + lrow;     // tile row 0..127
        int arow = sl[min(m0 + r, rows - 1)];
        asrc[j] = Hin + (size_t)arow * IDIM + lchunk * 8;
        bsrc[j] = Wd + (size_t)(n0 + r) * IDIM + lchunk * 8;
    }
    f32x4 acc[4][4];
    for (int a = 0; a < 4; a++)
        for (int b = 0; b < 4; b++) acc[a][b] = (f32x4){0.f, 0.f, 0.f, 0.f};
    int wm = wave >> 1, wn = wave & 1;
    int lm = lane & 15, quad = lane >> 4, x7 = lm & 7;

    for (int k0 = 0; k0 < IDIM; k0 += 64) {
        for (int j = 0; j < 4; j++) {
            gl_lds16(asrc[j] + k0, As + (wave * 4 + j) * 512);
            gl_lds16(bsrc[j] + k0, Bs + (wave * 4 + j) * 512);
        }
        __syncthreads();
        for (int kk = 0; kk < 2; kk++) {
            int cg = ((kk * 4 + quad) ^ x7) * 8;
            bf16x8 af[4], bf_[4];
            for (int mi = 0; mi < 4; mi++)
                af[mi] = *(const bf16x8*)&As[(wm * 64 + mi * 16 + lm) * 64 + cg];
            for (int ni = 0; ni < 4; ni++)
                bf_[ni] = *(const bf16x8*)&Bs[(wn * 64 + ni * 16 + lm) * 64 + cg];
            for (int mi = 0; mi < 4; mi++)
                for (int ni = 0; ni < 4; ni++)
                    acc[mi][ni] = __builtin_amdgcn_mfma_f32_16x16x32_bf16(af[mi], bf_[ni],
                                                                          acc[mi][ni], 0, 0, 0);
        }
        __syncthreads();
    }
    for (int mi = 0; mi < 4; mi++)
        for (int j = 0; j < 4; j++) {
            int r = m0 + wm * 64 + mi * 16 + quad * 4 + j;
            if (r >= rows) continue;
            int srow = sl[r];
            bf16_t* op = Eout + (size_t)srow * HDIM + n0 + wn * 64 + lm;
            for (int ni = 0; ni < 4; ni++) op[ni * 16] = (bf16_t)acc[mi][ni][j];
        }
}

// ---------------- combine: out[t] = eout[2t] + eout[2t+1] + eout[2T+t] ----------------
__global__ __launch_bounds__(256) void k_combine(const bf16_t* __restrict__ Eout,
                                                 float* __restrict__ Out) {
    size_t i = ((size_t)blockIdx.x * 256 + threadIdx.x) * 8;
    size_t t = i / HDIM, h = i % HDIM;
    bf16x8 a = *(const bf16x8*)(Eout + (2 * t) * HDIM + h);
    bf16x8 b = *(const bf16x8*)(Eout + (2 * t + 1) * HDIM + h);
    bf16x8 c = *(const bf16x8*)(Eout + (size_t)(2 * TTOK + t) * HDIM + h);
    float* op = Out + i;
    for (int j = 0; j < 8; j++) op[j] = (float)a[j] + (float)b[j] + (float)c[j];
}

extern "C" void kernel_launch(void* const* d_in, const int* in_sizes, int n_in,
                              void* d_out, int out_size, void* d_ws, size_t ws_size,
                              hipStream_t stream) {
    const float* x = (const float*)d_in[0];
    const float* tcx = (const float*)d_in[1];
    const float* tp_w = (const float*)d_in[2];
    const float* tp_b = (const float*)d_in[3];
    const float* gate_w = (const float*)d_in[4];
    const float* eg = (const float*)d_in[5];
    const float* eu = (const float*)d_in[6];
    const float* ed = (const float*)d_in[7];
    const float* sg = (const float*)d_in[8];
    const float* su = (const float*)d_in[9];
    const float* sd = (const float*)d_in[10];
    float* out = (float*)d_out;

    char* wsp = (char*)d_ws;
    size_t off = 0;
    auto alloc = [&](size_t b) -> void* {
        void* p = wsp + off;
        off += (b + 255) & ~(size_t)255;
        return p;
    };
    bf16_t* xb = (bf16_t*)alloc((size_t)TTOK * HDIM * 2);
    bf16_t* WgT = (bf16_t*)alloc((size_t)NEXP1 * IDIM * HDIM * 2);   // experts 0..7 + shared @8
    bf16_t* WuT = (bf16_t*)alloc((size_t)NEXP1 * IDIM * HDIM * 2);
    bf16_t* WdT = (bf16_t*)alloc((size_t)NEXP1 * HDIM * IDIM * 2);
    float* A_r = (float*)alloc(HDIM * NEXP * 4);
    float* bg = (float*)alloc(NEXP * 4);
    int* cnt = (int*)alloc(NEXP1 * 4);
    int* tok = (int*)alloc(NEXP1 * TTOK * 4);
    float* wl = (float*)alloc(NEXP1 * TTOK * 4);
    int* sl = (int*)alloc(NEXP1 * TTOK * 4);
    bf16_t* hbuf = (bf16_t*)alloc((size_t)3 * TTOK * IDIM * 2);      // rows = slot in [0,3T)
    bf16_t* eout = (bf16_t*)alloc((size_t)3 * TTOK * HDIM * 2);

    hipMemsetAsync(cnt, 0, NEXP1 * 4, stream);
    k_convert<<<TTOK * HDIM / 1024, 256, 0, stream>>>(x, xb);
    k_tr_HI<<<dim3(IDIM / 64, HDIM / 128, 18), 256, 0, stream>>>(eg, eu, sg, su, WgT, WuT);
    k_tr_IH<<<dim3(HDIM / 64, IDIM / 128, 9), 256, 0, stream>>>(ed, sd, WdT);
    k_router_prep<<<33, 256, 0, stream>>>(tp_w, tp_b, gate_w, A_r, bg);
    k_router<<<TTOK / 4, 256, 0, stream>>>(x, tcx, gate_w, A_r, bg, cnt, tok, wl, sl);
    k_gateup<<<dim3(IDIM / 128, TTOK / 128, NEXP1), 256, 0, stream>>>(xb, WgT, WuT, hbuf, tok, wl,
                                                                      sl, cnt);
    k_down<<<dim3(HDIM / 128, TTOK / 128, NEXP1), 256, 0, stream>>>(hbuf, WdT, eout, sl, cnt);
    k_combine<<<TTOK * HDIM / 2048, 256, 0, stream>>>(eout, out);
    (void)in_sizes; (void)n_in; (void)out_size; (void)ws_size;
}

// Round 6
// 619.912 us; speedup vs baseline: 1.0573x; 1.0573x over previous
//
#include <hip/hip_runtime.h>
#include <hip/hip_bf16.h>
#include <stdint.h>

#define HDIM 1024
#define IDIM 2048
#define NEXP 8
#define NEXP1 9      // 8 routed + 1 shared (index 8)
#define TTOK 4096
#define REPS 1e-5f

typedef __bf16 bf16_t;
typedef __bf16 bf16x8 __attribute__((ext_vector_type(8)));
typedef __bf16 bf16x4 __attribute__((ext_vector_type(4)));
typedef float f32x4 __attribute__((ext_vector_type(4)));

// async global->LDS DMA, 16 B per lane. dst must be wave-uniform; HW adds lane*16.
__device__ __forceinline__ void gl_lds16(const bf16_t* g, bf16_t* l) {
    __builtin_amdgcn_global_load_lds(
        (const __attribute__((address_space(1))) void*)g,
        (__attribute__((address_space(3))) void*)l, 16, 0, 0);
}

// ---------------- fp32 -> bf16 convert (contiguous) ----------------
__global__ __launch_bounds__(256) void k_convert(const float* __restrict__ src,
                                                 bf16_t* __restrict__ dst) {
    size_t i = ((size_t)blockIdx.x * 256 + threadIdx.x) * 4;
    float4 v = *(const float4*)(src + i);
    bf16x4 o = {(__bf16)v.x, (__bf16)v.y, (__bf16)v.z, (__bf16)v.w};
    *(bf16x4*)(dst + i) = o;
}

// ---- transpose core: src [R][C] f32 -> dst [C][R] bf16, one 128(row)x64(col) tile ----
__device__ __forceinline__ void tr_tile(const float* __restrict__ src, bf16_t* __restrict__ dst,
                                        int R, int C, int c0, int r0, bf16_t* lds) {
    int tid = threadIdx.x;
    // phase 1: lane loads float4, converts, 8B store to XOR-swizzled chunk
    int rlo = tid >> 4, chunk = tid & 15;
    for (int p = 0; p < 8; p++) {
        int r = p * 16 + rlo;
        float4 v = *(const float4*)(src + (size_t)(r0 + r) * C + c0 + chunk * 4);
        bf16x4 o = {(__bf16)v.x, (__bf16)v.y, (__bf16)v.z, (__bf16)v.w};
        *(bf16x4*)(lds + r * 64 + (chunk ^ (p & 7)) * 4) = o;
    }
    __syncthreads();
    // phase 2: thread = (col-pair c2 0..31, row-half rh 0..7); b32 reads, pack, 32B col stores
    int c2 = tid & 31, rh = tid >> 5;
    uint32_t d[16];
    for (int i = 0; i < 16; i++) {
        int r = rh * 16 + i;
        d[i] = *(const uint32_t*)(lds + r * 64 + ((c2 >> 1) ^ (rh & 7)) * 4 + (c2 & 1) * 2);
    }
    uint32_t o0[8], o1[8];
    for (int j = 0; j < 8; j++) {
        uint32_t a = d[2 * j], b = d[2 * j + 1];
        o0[j] = (a & 0xffffu) | (b << 16);
        o1[j] = (a >> 16) | (b & 0xffff0000u);
    }
    bf16_t* p0 = dst + (size_t)(c0 + 2 * c2) * R + r0 + rh * 16;
    bf16_t* p1 = p0 + R;
    *(uint4*)p0 = *(uint4*)&o0[0];
    *(uint4*)(p0 + 8) = *(uint4*)&o0[4];
    *(uint4*)p1 = *(uint4*)&o1[0];
    *(uint4*)(p1 + 8) = *(uint4*)&o1[4];
}

// [H][I] sources (eg, eu, sg, su) -> [I][H] bf16. z: 0..7 eg, 8..15 eu, 16 sg, 17 su.
__global__ __launch_bounds__(256) void k_tr_HI(const float* __restrict__ eg,
                                               const float* __restrict__ eu,
                                               const float* __restrict__ sg,
                                               const float* __restrict__ su,
                                               bf16_t* __restrict__ WgT,
                                               bf16_t* __restrict__ WuT) {
    __shared__ __align__(16) bf16_t lds[128 * 64];
    int z = blockIdx.z;
    const float* src;
    bf16_t* dst;
    size_t msz = (size_t)HDIM * IDIM;
    if (z < 8)       { src = eg + z * msz;        dst = WgT + z * msz; }
    else if (z < 16) { src = eu + (z - 8) * msz;  dst = WuT + (z - 8) * msz; }
    else if (z == 16){ src = sg;                  dst = WgT + 8 * msz; }
    else             { src = su;                  dst = WuT + 8 * msz; }
    tr_tile(src, dst, HDIM, IDIM, blockIdx.x * 64, blockIdx.y * 128, lds);
}

// [I][H] sources (ed, sd) -> [H][I] bf16. z: 0..7 ed, 8 sd.
__global__ __launch_bounds__(256) void k_tr_IH(const float* __restrict__ ed,
                                               const float* __restrict__ sd,
                                               bf16_t* __restrict__ WdT) {
    __shared__ __align__(16) bf16_t lds[128 * 64];
    int z = blockIdx.z;
    size_t msz = (size_t)HDIM * IDIM;
    const float* src = (z < 8) ? ed + z * msz : sd;
    bf16_t* dst = WdT + ((z < 8) ? z : 8) * msz;
    tr_tile(src, dst, IDIM, HDIM, blockIdx.x * 64, blockIdx.y * 128, lds);
}

// ---------------- router prep: A = tp_w @ gate_w [H,8]; bg = tp_b @ gate_w [8] ----------------
// One wave per output element; lanes split the K=1024 sum (coalesced), butterfly reduce.
__global__ __launch_bounds__(256) void k_router_prep(const float* __restrict__ tp_w,
                                                     const float* __restrict__ tp_b,
                                                     const float* __restrict__ gw,
                                                     float* __restrict__ A_r,
                                                     float* __restrict__ bg) {
    int widx = blockIdx.x * 4 + (threadIdx.x >> 6);
    int lane = threadIdx.x & 63;
    if (widx >= HDIM * NEXP + NEXP) return;
    const float* vec;
    int e;
    if (widx < HDIM * NEXP) {
        vec = tp_w + (size_t)(widx >> 3) * HDIM;
        e = widx & 7;
    } else {
        vec = tp_b;
        e = widx - HDIM * NEXP;
    }
    float acc = 0.f;
    for (int j = lane; j < HDIM; j += 64) acc = fmaf(vec[j], gw[j * NEXP + e], acc);
    for (int off = 32; off > 0; off >>= 1) acc += __shfl_xor(acc, off);
    if (lane == 0) {
        if (widx < HDIM * NEXP) A_r[widx] = acc;
        else bg[e] = acc;
    }
}

// ---------------- router: logits, softmax, top-2, bucket by expert (+ shared-expert fill) -----
__global__ __launch_bounds__(256) void k_router(const float* __restrict__ x,
                                                const float* __restrict__ tcx,
                                                const float* __restrict__ gw,
                                                const float* __restrict__ A_r,
                                                const float* __restrict__ bg,
                                                int* __restrict__ cnt, int* __restrict__ tok,
                                                float* __restrict__ wl, int* __restrict__ sl) {
    int wave = threadIdx.x >> 6, lane = threadIdx.x & 63;
    int t = blockIdx.x * 4 + wave;
    const float* xr = x + (size_t)t * HDIM;
    const float* tr = tcx + (size_t)t * HDIM;
    float lg[NEXP];
    for (int e = 0; e < NEXP; e++) lg[e] = 0.f;
    for (int h = lane; h < HDIM; h += 64) {
        float xv = xr[h], tv = tr[h];
        const float4* g4 = (const float4*)(gw + h * NEXP);
        const float4* a4 = (const float4*)(A_r + h * NEXP);
        float4 g0 = g4[0], g1 = g4[1], a0 = a4[0], a1 = a4[1];
        lg[0] += xv * g0.x + tv * a0.x;
        lg[1] += xv * g0.y + tv * a0.y;
        lg[2] += xv * g0.z + tv * a0.z;
        lg[3] += xv * g0.w + tv * a0.w;
        lg[4] += xv * g1.x + tv * a1.x;
        lg[5] += xv * g1.y + tv * a1.y;
        lg[6] += xv * g1.z + tv * a1.z;
        lg[7] += xv * g1.w + tv * a1.w;
    }
    for (int off = 32; off > 0; off >>= 1)
        for (int e = 0; e < NEXP; e++) lg[e] += __shfl_xor(lg[e], off);
    if (lane == 1) {  // shared-expert identity entry (fused former k_fill_shared)
        tok[NEXP * TTOK + t] = t;
        wl[NEXP * TTOK + t] = 1.f;
        sl[NEXP * TTOK + t] = 2 * TTOK + t;
        if (t == 0) cnt[NEXP] = TTOK;
    }
    if (lane == 0) {
        float m = -1e30f;
        for (int e = 0; e < NEXP; e++) {
            lg[e] += bg[e];
            m = fmaxf(m, lg[e]);
        }
        float p[NEXP], Z = 0.f;
        for (int e = 0; e < NEXP; e++) {
            p[e] = __expf(lg[e] - m);
            Z += p[e];
        }
        for (int e = 0; e < NEXP; e++) p[e] /= Z;
        int i1 = 0;
        float b1 = p[0];
        for (int e = 1; e < NEXP; e++)
            if (p[e] > b1) { b1 = p[e]; i1 = e; }   // strict > : lowest index wins ties (jax top_k)
        int i2 = -1;
        float b2 = -1.f;
        for (int e = 0; e < NEXP; e++) {
            if (e == i1) continue;
            if (p[e] > b2) { b2 = p[e]; i2 = e; }
        }
        float s = b1 + b2 + REPS;
        float w1 = b1 / s, w2 = b2 / s;
        int p1 = atomicAdd(&cnt[i1], 1);
        tok[i1 * TTOK + p1] = t;
        wl[i1 * TTOK + p1] = w1;
        sl[i1 * TTOK + p1] = 2 * t;
        int p2 = atomicAdd(&cnt[i2], 1);
        tok[i2 * TTOK + p2] = t;
        wl[i2 * TTOK + p2] = w2;
        sl[i2 * TTOK + p2] = 2 * t + 1;
    }
}

// ---------------- gate/up GEMM, BM=128 BN=64 (async LDS staging, xor-swizzled) ----------------
__global__ __launch_bounds__(256, 2) void k_gateup(const bf16_t* __restrict__ Xb,
                                                   const bf16_t* __restrict__ WgT,
                                                   const bf16_t* __restrict__ WuT,
                                                   bf16_t* __restrict__ Hout,
                                                   const int* __restrict__ tok_l,
                                                   const float* __restrict__ w_l,
                                                   const int* __restrict__ slot_l,
                                                   const int* __restrict__ cnt) {
    int e = blockIdx.z;
    int rows = cnt[e];
    int m0 = blockIdx.y * 128;
    if (m0 >= rows) return;
    int n0 = blockIdx.x * 64;
    const bf16_t* Wg = WgT + (size_t)e * IDIM * HDIM;
    const bf16_t* Wu = WuT + (size_t)e * IDIM * HDIM;
    const int* tl = tok_l + e * TTOK;
    const float* wlp = w_l + e * TTOK;
    const int* sl = slot_l + e * TTOK;

    __shared__ __align__(16) bf16_t As[128 * 64];
    __shared__ __align__(16) bf16_t Bg[64 * 64];
    __shared__ __align__(16) bf16_t Bu[64 * 64];

    int tid = threadIdx.x;
    int lane = tid & 63, wave = tid >> 6;
    int lrow = lane >> 3;                      // 0..7 within an issue
    int lchunk = (lane & 7) ^ lrow;            // inverse swizzle on the source side

    const bf16_t* asrc[4];
    for (int j = 0; j < 4; j++) {
        int r = (wave * 4 + j) * 8 + lrow;     // tile row 0..127
        int row = tl[min(m0 + r, rows - 1)];
        asrc[j] = Xb + (size_t)row * HDIM + lchunk * 8;
    }
    const bf16_t* gsrc[2];
    const bf16_t* usrc[2];
    for (int j = 0; j < 2; j++) {
        int r = (wave * 2 + j) * 8 + lrow;     // tile row 0..63
        gsrc[j] = Wg + (size_t)(n0 + r) * HDIM + lchunk * 8;
        usrc[j] = Wu + (size_t)(n0 + r) * HDIM + lchunk * 8;
    }

    f32x4 accg[2][4], accu[2][4];
    for (int a = 0; a < 2; a++)
        for (int b = 0; b < 4; b++) {
            accg[a][b] = (f32x4){0.f, 0.f, 0.f, 0.f};
            accu[a][b] = (f32x4){0.f, 0.f, 0.f, 0.f};
        }
    int lm = lane & 15, quad = lane >> 4, x7 = lm & 7;

    for (int k0 = 0; k0 < HDIM; k0 += 64) {
        for (int j = 0; j < 4; j++) gl_lds16(asrc[j] + k0, As + (wave * 4 + j) * 512);
        for (int j = 0; j < 2; j++) {
            gl_lds16(gsrc[j] + k0, Bg + (wave * 2 + j) * 512);
            gl_lds16(usrc[j] + k0, Bu + (wave * 2 + j) * 512);
        }
        __syncthreads();
        for (int kk = 0; kk < 2; kk++) {
            int cg = ((kk * 4 + quad) ^ x7) * 8;
            bf16x8 af[2], bgf[4], buf_[4];
            for (int mi = 0; mi < 2; mi++)
                af[mi] = *(const bf16x8*)&As[(wave * 32 + mi * 16 + lm) * 64 + cg];
            for (int ni = 0; ni < 4; ni++) {
                bgf[ni] = *(const bf16x8*)&Bg[(ni * 16 + lm) * 64 + cg];
                buf_[ni] = *(const bf16x8*)&Bu[(ni * 16 + lm) * 64 + cg];
            }
            for (int mi = 0; mi < 2; mi++)
                for (int ni = 0; ni < 4; ni++) {
                    accg[mi][ni] = __builtin_amdgcn_mfma_f32_16x16x32_bf16(af[mi], bgf[ni],
                                                                           accg[mi][ni], 0, 0, 0);
                    accu[mi][ni] = __builtin_amdgcn_mfma_f32_16x16x32_bf16(af[mi], buf_[ni],
                                                                           accu[mi][ni], 0, 0, 0);
                }
        }
        __syncthreads();
    }
    for (int mi = 0; mi < 2; mi++)
        for (int j = 0; j < 4; j++) {
            int r = m0 + wave * 32 + mi * 16 + quad * 4 + j;  // C/D: row = quad*4+reg
            if (r >= rows) continue;
            int srow = sl[r];
            float w = wlp[r];
            bf16_t* hp = Hout + (size_t)srow * IDIM + n0 + lm;  // col = lane&15
            for (int ni = 0; ni < 4; ni++) {
                float g = accg[mi][ni][j];
                float u = accu[mi][ni][j];
                hp[ni * 16] = (bf16_t)(g / (1.f + __expf(-g)) * u * w);
            }
        }
}

// ---------------- down GEMM: eout[slot] = h[slot] @ Wd (async staging, swizzled) ----------------
__global__ __launch_bounds__(256, 2) void k_down(const bf16_t* __restrict__ Hin,
                                                 const bf16_t* __restrict__ WdT,
                                                 bf16_t* __restrict__ Eout,
                                                 const int* __restrict__ slot_l,
                                                 const int* __restrict__ cnt) {
    int e = blockIdx.z;
    int rows = cnt[e];
    int m0 = blockIdx.y * 128;
    if (m0 >= rows) return;
    int n0 = blockIdx.x * 128;
    const bf16_t* Wd = WdT + (size_t)e * HDIM * IDIM;
    const int* sl = slot_l + e * TTOK;

    __shared__ __align__(16) bf16_t As[128 * 64];
    __shared__ __align__(16) bf16_t Bs[128 * 64];

    int tid = threadIdx.x, lane = tid & 63, wave = tid >> 6;
    int lrow = lane >> 3;
    int lchunk = (lane & 7) ^ lrow;

    const bf16_t* asrc[4];
    const bf16_t* bsrc[4];
    for (int j = 0; j < 4; j++) {
        int r = (wave * 4 + j) * 8 + lrow;     // tile row 0..127
        int arow = sl[min(m0 + r, rows - 1)];
        asrc[j] = Hin + (size_t)arow * IDIM + lchunk * 8;
        bsrc[j] = Wd + (size_t)(n0 + r) * IDIM + lchunk * 8;
    }
    f32x4 acc[4][4];
    for (int a = 0; a < 4; a++)
        for (int b = 0; b < 4; b++) acc[a][b] = (f32x4){0.f, 0.f, 0.f, 0.f};
    int wm = wave >> 1, wn = wave & 1;
    int lm = lane & 15, quad = lane >> 4, x7 = lm & 7;

    for (int k0 = 0; k0 < IDIM; k0 += 64) {
        for (int j = 0; j < 4; j++) {
            gl_lds16(asrc[j] + k0, As + (wave * 4 + j) * 512);
            gl_lds16(bsrc[j] + k0, Bs + (wave * 4 + j) * 512);
        }
        __syncthreads();
        for (int kk = 0; kk < 2; kk++) {
            int cg = ((kk * 4 + quad) ^ x7) * 8;
            bf16x8 af[4], bf_[4];
            for (int mi = 0; mi < 4; mi++)
                af[mi] = *(const bf16x8*)&As[(wm * 64 + mi * 16 + lm) * 64 + cg];
            for (int ni = 0; ni < 4; ni++)
                bf_[ni] = *(const bf16x8*)&Bs[(wn * 64 + ni * 16 + lm) * 64 + cg];
            for (int mi = 0; mi < 4; mi++)
                for (int ni = 0; ni < 4; ni++)
                    acc[mi][ni] = __builtin_amdgcn_mfma_f32_16x16x32_bf16(af[mi], bf_[ni],
                                                                          acc[mi][ni], 0, 0, 0);
        }
        __syncthreads();
    }
    for (int mi = 0; mi < 4; mi++)
        for (int j = 0; j < 4; j++) {
            int r = m0 + wm * 64 + mi * 16 + quad * 4 + j;
            if (r >= rows) continue;
            int srow = sl[r];
            bf16_t* op = Eout + (size_t)srow * HDIM + n0 + wn * 64 + lm;
            for (int ni = 0; ni < 4; ni++) op[ni * 16] = (bf16_t)acc[mi][ni][j];
        }
}

// ---------------- combine: out[t] = eout[2t] + eout[2t+1] + eout[2T+t] ----------------
__global__ __launch_bounds__(256) void k_combine(const bf16_t* __restrict__ Eout,
                                                 float* __restrict__ Out) {
    size_t i = ((size_t)blockIdx.x * 256 + threadIdx.x) * 8;
    size_t t = i / HDIM, h = i % HDIM;
    bf16x8 a = *(const bf16x8*)(Eout + (2 * t) * HDIM + h);
    bf16x8 b = *(const bf16x8*)(Eout + (2 * t + 1) * HDIM + h);
    bf16x8 c = *(const bf16x8*)(Eout + (size_t)(2 * TTOK + t) * HDIM + h);
    float* op = Out + i;
    for (int j = 0; j < 8; j++) op[j] = (float)a[j] + (float)b[j] + (float)c[j];
}

extern "C" void kernel_launch(void* const* d_in, const int* in_sizes, int n_in,
                              void* d_out, int out_size, void* d_ws, size_t ws_size,
                              hipStream_t stream) {
    const float* x = (const float*)d_in[0];
    const float* tcx = (const float*)d_in[1];
    const float* tp_w = (const float*)d_in[2];
    const float* tp_b = (const float*)d_in[3];
    const float* gate_w = (const float*)d_in[4];
    const float* eg = (const float*)d_in[5];
    const float* eu = (const float*)d_in[6];
    const float* ed = (const float*)d_in[7];
    const float* sg = (const float*)d_in[8];
    const float* su = (const float*)d_in[9];
    const float* sd = (const float*)d_in[10];
    float* out = (float*)d_out;

    char* wsp = (char*)d_ws;
    size_t off = 0;
    auto alloc = [&](size_t b) -> void* {
        void* p = wsp + off;
        off += (b + 255) & ~(size_t)255;
        return p;
    };
    bf16_t* xb = (bf16_t*)alloc((size_t)TTOK * HDIM * 2);
    bf16_t* WgT = (bf16_t*)alloc((size_t)NEXP1 * IDIM * HDIM * 2);   // experts 0..7 + shared @8
    bf16_t* WuT = (bf16_t*)alloc((size_t)NEXP1 * IDIM * HDIM * 2);
    bf16_t* WdT = (bf16_t*)alloc((size_t)NEXP1 * HDIM * IDIM * 2);
    float* A_r = (float*)alloc(HDIM * NEXP * 4);
    float* bg = (float*)alloc(NEXP * 4);
    int* cnt = (int*)alloc(NEXP1 * 4);
    int* tok = (int*)alloc(NEXP1 * TTOK * 4);
    float* wl = (float*)alloc(NEXP1 * TTOK * 4);
    int* sl = (int*)alloc(NEXP1 * TTOK * 4);
    bf16_t* hbuf = (bf16_t*)alloc((size_t)3 * TTOK * IDIM * 2);      // rows = slot in [0,3T)
    bf16_t* eout = (bf16_t*)alloc((size_t)3 * TTOK * HDIM * 2);

    hipMemsetAsync(cnt, 0, NEXP1 * 4, stream);
    k_convert<<<TTOK * HDIM / 1024, 256, 0, stream>>>(x, xb);
    k_tr_HI<<<dim3(IDIM / 64, HDIM / 128, 18), 256, 0, stream>>>(eg, eu, sg, su, WgT, WuT);
    k_tr_IH<<<dim3(HDIM / 64, IDIM / 128, 9), 256, 0, stream>>>(ed, sd, WdT);
    k_router_prep<<<(HDIM * NEXP + NEXP + 3) / 4, 256, 0, stream>>>(tp_w, tp_b, gate_w, A_r, bg);
    k_router<<<TTOK / 4, 256, 0, stream>>>(x, tcx, gate_w, A_r, bg, cnt, tok, wl, sl);
    k_gateup<<<dim3(IDIM / 64, TTOK / 128, NEXP1), 256, 0, stream>>>(xb, WgT, WuT, hbuf, tok, wl,
                                                                     sl, cnt);
    k_down<<<dim3(HDIM / 128, TTOK / 128, NEXP1), 256, 0, stream>>>(hbuf, WdT, eout, sl, cnt);
    k_combine<<<TTOK * HDIM / 2048, 256, 0, stream>>>(eout, out);
    (void)in_sizes; (void)n_in; (void)out_size; (void)ws_size;
}